// Round 4
// baseline (4025.262 us; speedup 1.0000x reference)
//
#include <hip/hip_runtime.h>
#include <hip/hip_bf16.h>
#include <cstdint>
#include <cstddef>

// 3-layer LSTM (T=128, B=256, IN=512, H=1024/1024/512) — round 11: LAUNCH-PER-PHASE.
// History: persistent-kernel phases stuck at ~32 µs while bottom-up issue model says
// ~4-6 µs of work; insensitive to fences (r8/r9), inv count (r9), prefetch depth (r10),
// L2 warm (r10), work distribution (r6) => ~26 µs/phase of all-idle time inside the
// software barrier machinery. This round DELETES the software barrier: each phase is
// its own kernel launch (130 launches, p=-1..128); the CP's end-of-kernel drain +
// L2 WB/INV between dependent dispatches IS the global barrier, done in hardware.
//  - weights re-staged into LDS per launch via async global_load_lds (16B/lane),
//    issued before anything else so panel loads start under its shadow.
//  - c-state lives in global between launches (12KB/block round-trip, negligible).
//  - all atomics/fences/census/spins removed; h-stores are plain stores.
// Compute core (GEMM + fused cell) unchanged => absmax must stay 0.00390625.

typedef __attribute__((ext_vector_type(8))) short short8;
typedef __attribute__((ext_vector_type(4))) short short4v;
typedef __attribute__((ext_vector_type(4))) float floatx4;

#define NTHR 1024

// ---------------- helpers ----------------
__device__ __forceinline__ float fsig(float x) {
    x = fminf(fmaxf(x, -30.f), 30.f);
    return 1.f / (1.f + __expf(-x));
}
__device__ __forceinline__ float ftanh(float x) {
    x = fminf(fmaxf(x, -15.f), 15.f);
    float e = __expf(2.f * x);
    return (e - 1.f) / (e + 1.f);
}

// async global->LDS, 16B per lane; lds dest = wave-uniform base + lane*16.
__device__ __forceinline__ void stage16(const void* gptr, void* lptr) {
    __builtin_amdgcn_global_load_lds(
        (const __attribute__((address_space(1))) unsigned int*)gptr,
        (__attribute__((address_space(3))) unsigned int*)lptr,
        16, 0, 0);
}

// ---------------- pack kernels ----------------
// Frag-ordered weight pack: dst[tile][kc][slot] of short8, 16 cols per tile.
// slot = lane: du=slot&3, g=(slot>>2)&3, ksub=slot>>4. unit = tile*4+du.
template<int K1, int K2, int H>
__global__ void pack_frag_kernel(const float* __restrict__ Wih,
                                 const float* __restrict__ Whh,
                                 __hip_bfloat16* __restrict__ dst) {
    constexpr int NK = (K1 + K2) / 32;
    constexpr int NTT = H / 4;
    int idx = blockIdx.x * 256 + threadIdx.x;
    if (idx >= NTT * NK * 64) return;
    int slot = idx & 63;
    int kc = (idx >> 6) % NK;
    int b = idx / (64 * NK);
    int du = slot & 3, g = (slot >> 2) & 3, ksub = slot >> 4;
    int unit = b * 4 + du;
    int j = g * H + unit;
    int k0 = kc * 32 + ksub * 8;
    __hip_bfloat16 tmp[8];
#pragma unroll
    for (int e = 0; e < 8; ++e) {
        int k = k0 + e;
        float v = (k < K1) ? Wih[(size_t)j * K1 + k] : Whh[(size_t)j * K2 + (k - K1)];
        tmp[e] = __float2bfloat16(v);
    }
    *(short8*)(dst + (size_t)idx * 8) = *(short8*)tmp;
}

__global__ void pack_bias_kernel(const float* __restrict__ a,
                                 const float* __restrict__ b,
                                 int n, float* __restrict__ out) {
    int i = blockIdx.x * 256 + threadIdx.x;
    if (i < n) out[i] = a[i] + b[i];
}

// x[t][row][512] fp32 -> xs[t][s 0..63][row][8] bf16 (8-wide slabs).
__global__ void x_to_slab_kernel(const float* __restrict__ x,
                                 __hip_bfloat16* __restrict__ xs) {
    int idx = blockIdx.x * 256 + threadIdx.x;
    int j   = idx & 7;
    int row = (idx >> 3) & 255;
    int s   = (idx >> 11) & 63;
    int t   = idx >> 17;
    xs[idx] = __float2bfloat16(x[((size_t)(t * 256 + row)) * 512 + s * 8 + j]);
}

__global__ void zero_f32_kernel(float* p, int n) {
    int i = blockIdx.x * 256 + threadIdx.x;
    if (i < n) p[i] = 0.f;
}

// ---------------- A-fragment loaders ----------------
__device__ __forceinline__ short8 afrag8(const __hip_bfloat16* __restrict__ base, int k) {
    return *(const short8*)(base + (size_t)k * 8192);
}
__device__ __forceinline__ short8 afrag4(const __hip_bfloat16* __restrict__ base, int k) {
    const __hip_bfloat16* p = base + (size_t)k * 8192;
    short4v lo = *(const short4v*)p;
    short4v hi = *(const short4v*)(p + 1024);
    return (short8){lo.x, lo.y, lo.z, lo.w, hi.x, hi.y, hi.z, hi.w};
}

// ---------------- per-layer GEMM + fused cell ----------------
template<int NK1, int NK2, bool A2W4, int NT, int H, int TSTR>
__device__ __forceinline__ void run_layer(
    const short8* __restrict__ ldsw, int bslot0,
    const __hip_bfloat16* __restrict__ A1, const __hip_bfloat16* __restrict__ A2,
    const float (&bl)[NT],
    __hip_bfloat16* __restrict__ hs, int slab,
    float (&creg)[NT][4], int tbase, int lane, int wave,
    bool fin, float* __restrict__ ho, float* __restrict__ co)
{
    constexpr int NK = NK1 + NK2;
    constexpr int W = NT * 4;
    const int col = lane & 15, ksub = lane >> 4;
    const int row = wave * 16 + col;
    const __hip_bfloat16* __restrict__ a1 = A1 + ksub * 2048 + row * 8;
    const __hip_bfloat16* __restrict__ a2 = A2 + ksub * 2048 + (A2W4 ? row * 4 : row * 8);

    short8 rb[8];
#pragma unroll
    for (int i = 0; i < 8; ++i) rb[i] = afrag8(a1, i);   // NK1 >= 16 >= 8 always

    floatx4 acc[NT];
#pragma unroll
    for (int ti = 0; ti < NT; ++ti) acc[ti] = (floatx4){0.f, 0.f, 0.f, 0.f};

#pragma unroll 8
    for (int kc = 0; kc < NK; ++kc) {
#pragma unroll
        for (int ti = 0; ti < NT; ++ti)
            acc[ti] = __builtin_amdgcn_mfma_f32_16x16x32_bf16(
                rb[kc & 7], ldsw[bslot0 + ti * TSTR + kc * 64], acc[ti], 0, 0, 0);
        int kn = kc + 8;
        if (kn < NK)
            rb[kc & 7] = (kn < NK1) ? afrag8(a1, kn)
                        : (A2W4 ? afrag4(a2, kn - NK1) : afrag8(a2, kn - NK1));
    }

    // epilogue: C/D layout col=lane&15, row=(lane>>4)*4+r. Gates at cols 4*g+du.
    const int du = col & 3;
    const int sbase = ksub * 16 + du;
#pragma unroll
    for (int ti = 0; ti < NT; ++ti) {
        float avb[4];
#pragma unroll
        for (int r = 0; r < 4; ++r) avb[r] = acc[ti][r] + bl[ti];
#pragma unroll
        for (int r = 0; r < 4; ++r) {
            float gI = __shfl(avb[r], sbase);
            float gF = __shfl(avb[r], sbase + 4);
            float gG = __shfl(avb[r], sbase + 8);
            float gO = __shfl(avb[r], sbase + 12);
            float i_ = fsig(gI), f_ = fsig(gF), gg = ftanh(gG), o_ = fsig(gO);
            float cn = f_ * creg[ti][r] + i_ * gg;
            creg[ti][r] = cn;
            float hn = o_ * ftanh(cn);
            // pack two adjacent units into one plain 4B store: lanes col 0/2
            // store {col, col+1}; hn replicated across col-quads so lane+1 holds
            // the partner unit's value.
            __hip_bfloat16 hv = __float2bfloat16(hn);
            unsigned hb = (unsigned)*reinterpret_cast<unsigned short*>(&hv);
            unsigned hp = __shfl(hb, lane + 1);
            int orow = wave * 16 + ksub * 4 + r;
            if (col < 4) {
                if ((col & 1) == 0) {
                    unsigned pk = hb | (hp << 16);
                    size_t idx = ((size_t)slab * 256 + orow) * W + ti * 4 + col;
                    *(unsigned*)(hs + idx) = pk;
                }
                if (fin) {
                    int unit = (tbase + ti) * 4 + du;
                    ho[(size_t)orow * H + unit] = hn;
                    co[(size_t)orow * H + unit] = cn;
                }
            }
        }
    }
}

// ---------------- per-phase step kernel ----------------
// p = -1: group B only: l1(0).  p in [0,127]: A: l2(p); B: l1(p+1) (p<=126),
// l3(p-1) (p>=1).  p = 128: group B only: l3(127), final.
__global__ __launch_bounds__(NTHR, 4) void lstm_step(
    const __hip_bfloat16* __restrict__ xs,
    const __hip_bfloat16* __restrict__ w1f,
    const __hip_bfloat16* __restrict__ w2f,
    const __hip_bfloat16* __restrict__ w3f,
    const float* __restrict__ bc1, const float* __restrict__ bc2, const float* __restrict__ bc3,
    __hip_bfloat16* __restrict__ h1b, __hip_bfloat16* __restrict__ h2b,
    __hip_bfloat16* __restrict__ h3b,
    float* __restrict__ c1s, float* __restrict__ c2s, float* __restrict__ c3s,
    float* __restrict__ out, int p)
{
    __shared__ short8 ldsw[9216];   // A: w2 [0,8192). B: w1 [0,6144) + w3 [6144,9216)
    const int tid = threadIdx.x, blk = blockIdx.x;
    const int lane = tid & 63, wave = tid >> 6;
    const bool isA = blk < 128;
    const int sb = isA ? blk : (blk - 128);

    if (isA && (p < 0 || p > 127)) return;

    // ---- async weight staging: issue FIRST so everything else runs under it ----
    if (isA) {
        const char* gw = (const char*)w2f + (size_t)sb * 131072;   // 8192 short8
#pragma unroll
        for (int c = 0; c < 8; ++c)
            stage16(gw + ((size_t)((wave * 8 + c) * 64 + lane) * 16),
                    (char*)ldsw + (size_t)(wave * 8 + c) * 1024);
    } else {
        if (p <= 126) {
            const char* g1 = (const char*)w1f + (size_t)sb * 98304;   // 6144 short8
#pragma unroll
            for (int c = 0; c < 6; ++c)
                stage16(g1 + ((size_t)((wave * 6 + c) * 64 + lane) * 16),
                        (char*)ldsw + (size_t)(wave * 6 + c) * 1024);
        }
        if (p >= 1) {
            const char* g3 = (const char*)w3f + (size_t)sb * 49152;   // 3072 short8
#pragma unroll
            for (int c = 0; c < 3; ++c)
                stage16(g3 + ((size_t)((wave * 3 + c) * 64 + lane) * 16),
                        (char*)ldsw + 98304 + (size_t)(wave * 3 + c) * 1024);
        }
    }

    const int col = lane & 15, ksub = lane >> 4, du = col & 3, g = col >> 2;
    const int orow0 = wave * 16 + ksub * 4;

    float bl1[2], bl2[2], bl3[1];
    float c1r[2][4], c2r[2][4], c3r[1][4];

    if (isA) {
        bl2[0] = bc2[g * 1024 + (2 * sb + 0) * 4 + du];
        bl2[1] = bc2[g * 1024 + (2 * sb + 1) * 4 + du];
#pragma unroll
        for (int ti = 0; ti < 2; ++ti)
#pragma unroll
            for (int r = 0; r < 4; ++r)
                c2r[ti][r] = c2s[((size_t)sb * 256 + orow0 + r) * 8 + ti * 4 + du];
    } else {
        bl1[0] = bc1[g * 1024 + (2 * sb + 0) * 4 + du];
        bl1[1] = bc1[g * 1024 + (2 * sb + 1) * 4 + du];
        bl3[0] = bc3[g * 512 + sb * 4 + du];
#pragma unroll
        for (int ti = 0; ti < 2; ++ti)
#pragma unroll
            for (int r = 0; r < 4; ++r)
                c1r[ti][r] = c1s[((size_t)sb * 256 + orow0 + r) * 8 + ti * 4 + du];
#pragma unroll
        for (int r = 0; r < 4; ++r)
            c3r[0][r] = c3s[((size_t)sb * 256 + orow0 + r) * 4 + du];
    }

    // drain staging (and the small c/bias loads) before any wave reads ldsw
    asm volatile("s_waitcnt vmcnt(0)" ::: "memory");
    __syncthreads();

    float* h1o = out;
    float* c1o = out + 262144;
    float* h2o = out + 524288;
    float* c2o = out + 786432;
    float* h3o = out + 1048576;
    float* c3o = out + 1179648;

    const size_t cur = (size_t)(p & 1), prv = (size_t)((p + 1) & 1);

    if (isA) {
        run_layer<32, 32, false, 2, 1024, 4096>(ldsw, lane,
            h1b + cur * 262144, h2b + prv * 262144, bl2,
            h2b + cur * 262144, sb, c2r, 2 * sb, lane, wave, p == 127, h2o, c2o);
        if (col < 4) {
#pragma unroll
            for (int ti = 0; ti < 2; ++ti)
#pragma unroll
                for (int r = 0; r < 4; ++r)
                    c2s[((size_t)sb * 256 + orow0 + r) * 8 + ti * 4 + du] = c2r[ti][r];
        }
    } else {
        if (p <= 126) {
            run_layer<16, 32, false, 2, 1024, 3072>(ldsw, lane,
                xs + (size_t)(p + 1) * 131072, h1b + cur * 262144, bl1,
                h1b + prv * 262144, sb, c1r, 2 * sb, lane, wave, (p + 1) == 127, h1o, c1o);
            if (col < 4) {
#pragma unroll
                for (int ti = 0; ti < 2; ++ti)
#pragma unroll
                    for (int r = 0; r < 4; ++r)
                        c1s[((size_t)sb * 256 + orow0 + r) * 8 + ti * 4 + du] = c1r[ti][r];
            }
        }
        if (p >= 1) {
            run_layer<32, 16, true, 1, 512, 0>(ldsw, 6144 + lane,
                h2b + prv * 262144, h3b + cur * 131072, bl3,
                h3b + prv * 131072, sb, c3r, sb, lane, wave, p == 128, h3o, c3o);
            if (col < 4) {
#pragma unroll
                for (int r = 0; r < 4; ++r)
                    c3s[((size_t)sb * 256 + orow0 + r) * 4 + du] = c3r[0][r];
            }
        }
    }
}

// ---------------- launch ----------------
extern "C" void kernel_launch(void* const* d_in, const int* in_sizes, int n_in,
                              void* d_out, int out_size, void* d_ws, size_t ws_size,
                              hipStream_t stream) {
    const float* x    = (const float*)d_in[0];
    const float* Wih1 = (const float*)d_in[1];
    const float* Whh1 = (const float*)d_in[2];
    const float* bih1 = (const float*)d_in[3];
    const float* bhh1 = (const float*)d_in[4];
    const float* Wih2 = (const float*)d_in[5];
    const float* Whh2 = (const float*)d_in[6];
    const float* bih2 = (const float*)d_in[7];
    const float* bhh2 = (const float*)d_in[8];
    const float* Wih3 = (const float*)d_in[9];
    const float* Whh3 = (const float*)d_in[10];
    const float* bih3 = (const float*)d_in[11];
    const float* bhh3 = (const float*)d_in[12];
    float* out = (float*)d_out;

    char* p = (char*)d_ws;
    auto alloc = [&](size_t bytes) {
        char* r = p;
        p += (bytes + 255) & ~(size_t)255;
        return r;
    };
    __hip_bfloat16* xs  = (__hip_bfloat16*)alloc((size_t)128 * 64 * 256 * 8 * 2);
    __hip_bfloat16* w1f = (__hip_bfloat16*)alloc((size_t)256 * 48 * 64 * 8 * 2);
    __hip_bfloat16* w2f = (__hip_bfloat16*)alloc((size_t)256 * 64 * 64 * 8 * 2);
    __hip_bfloat16* w3f = (__hip_bfloat16*)alloc((size_t)128 * 48 * 64 * 8 * 2);
    float* bc1 = (float*)alloc(4096 * 4);
    float* bc2 = (float*)alloc(4096 * 4);
    float* bc3 = (float*)alloc(2048 * 4);
    __hip_bfloat16* h1b = (__hip_bfloat16*)alloc((size_t)2 * 262144 * 2);
    __hip_bfloat16* h2b = (__hip_bfloat16*)alloc((size_t)2 * 262144 * 2);
    __hip_bfloat16* h3b = (__hip_bfloat16*)alloc((size_t)2 * 131072 * 2);
    float* c1s = (float*)alloc((size_t)262144 * 4);
    float* c2s = (float*)alloc((size_t)262144 * 4);
    float* c3s = (float*)alloc((size_t)131072 * 4);

    auto blocks = [](int n) { return (n + 255) / 256; };

    pack_frag_kernel<512, 1024, 1024><<<blocks(256 * 48 * 64), 256, 0, stream>>>(Wih1, Whh1, w1f);
    pack_frag_kernel<1024, 1024, 1024><<<blocks(256 * 64 * 64), 256, 0, stream>>>(Wih2, Whh2, w2f);
    pack_frag_kernel<1024, 512, 512><<<blocks(128 * 48 * 64), 256, 0, stream>>>(Wih3, Whh3, w3f);
    pack_bias_kernel<<<blocks(4096), 256, 0, stream>>>(bih1, bhh1, 4096, bc1);
    pack_bias_kernel<<<blocks(4096), 256, 0, stream>>>(bih2, bhh2, 4096, bc2);
    pack_bias_kernel<<<blocks(2048), 256, 0, stream>>>(bih3, bhh3, 2048, bc3);
    x_to_slab_kernel<<<blocks(128 * 256 * 512), 256, 0, stream>>>(x, xs);
    zero_f32_kernel<<<blocks(262144), 256, 0, stream>>>((float*)h1b, 262144);
    zero_f32_kernel<<<blocks(262144), 256, 0, stream>>>((float*)h2b, 262144);
    zero_f32_kernel<<<blocks(131072), 256, 0, stream>>>((float*)h3b, 131072);
    zero_f32_kernel<<<blocks(262144), 256, 0, stream>>>(c1s, 262144);
    zero_f32_kernel<<<blocks(262144), 256, 0, stream>>>(c2s, 262144);
    zero_f32_kernel<<<blocks(131072), 256, 0, stream>>>(c3s, 131072);

    for (int ph = -1; ph <= 128; ++ph)
        lstm_step<<<256, NTHR, 0, stream>>>(xs, w1f, w2f, w3f, bc1, bc2, bc3,
                                            h1b, h2b, h3b, c1s, c2s, c3s, out, ph);
}